// Round 1
// baseline (24.093 us; speedup 1.0000x reference)
//
#include <hip/hip_runtime.h>

#define H_OBJ 64
#define W_OBJ 64
#define HIN 256
#define WIN 256
#define NCH 3

__global__ __launch_bounds__(256) void stn_glimpse_kernel(
    const float* __restrict__ image,   // [N,3,256,256]
    const float* __restrict__ zwhere,  // [N,4]  (y,x,h,w)
    const int* __restrict__ inv_p,     // [1]
    float* __restrict__ out)           // [N, 3*64*64]
{
    // 16 blocks of 256 threads per batch n (4096 pixels each)
    const int n   = blockIdx.x >> 4;
    const int pix = ((blockIdx.x & 15) << 8) + threadIdx.x;
    const int i   = pix >> 6;   // output row
    const int j   = pix & 63;   // output col

    const float zy = zwhere[n * 4 + 0];
    const float zx = zwhere[n * 4 + 1];
    const float zh = zwhere[n * 4 + 2];
    const float zw = zwhere[n * 4 + 3];
    const float y  = zy * 2.0f - 1.0f;
    const float x  = zx * 2.0f - 1.0f;

    const float gx = -1.0f + (2.0f / 63.0f) * (float)j;
    const float gy = -1.0f + (2.0f / 63.0f) * (float)i;

    const int inv = *inv_p;   // wave-uniform branch
    float grid_x, grid_y;
    if (inv) {
        grid_x = (gx - x) / zw;
        grid_y = (gy - y) / zh;
    } else {
        grid_x = zw * gx + x;
        grid_y = zh * gy + y;
    }

    float ix = (grid_x + 1.0f) * 0.5f * (float)(WIN - 1);
    float iy = (grid_y + 1.0f) * 0.5f * (float)(HIN - 1);
    ix = fminf(fmaxf(ix, 0.0f), (float)(WIN - 1));
    iy = fminf(fmaxf(iy, 0.0f), (float)(HIN - 1));

    const float ix0f = floorf(ix);
    const float iy0f = floorf(iy);
    const float wx = ix - ix0f;
    const float wy = iy - iy0f;
    const int ix0 = (int)ix0f;
    const int iy0 = (int)iy0f;
    const int ix1 = min(ix0 + 1, WIN - 1);
    const int iy1 = min(iy0 + 1, HIN - 1);

    const float w00 = (1.0f - wx) * (1.0f - wy);
    const float w01 = wx * (1.0f - wy);
    const float w10 = (1.0f - wx) * wy;
    const float w11 = wx * wy;

    const float* imgN = image + (size_t)n * NCH * HIN * WIN;
    float* outN = out + (size_t)n * NCH * (H_OBJ * W_OBJ) + pix;

    const int o00 = iy0 * WIN + ix0;
    const int o01 = iy0 * WIN + ix1;
    const int o10 = iy1 * WIN + ix0;
    const int o11 = iy1 * WIN + ix1;

#pragma unroll
    for (int c = 0; c < NCH; ++c) {
        const float* ch = imgN + c * (HIN * WIN);
        const float v00 = ch[o00];
        const float v01 = ch[o01];
        const float v10 = ch[o10];
        const float v11 = ch[o11];
        outN[c * (H_OBJ * W_OBJ)] =
            v00 * w00 + v01 * w01 + v10 * w10 + v11 * w11;
    }
}

extern "C" void kernel_launch(void* const* d_in, const int* in_sizes, int n_in,
                              void* d_out, int out_size, void* d_ws, size_t ws_size,
                              hipStream_t stream) {
    const float* image  = (const float*)d_in[0];
    const float* zwhere = (const float*)d_in[1];
    const int*   inv    = (const int*)d_in[2];
    float*       out    = (float*)d_out;

    // N = 512 batches, 16 blocks/batch
    const int nBatch = in_sizes[1] / 4;
    stn_glimpse_kernel<<<nBatch * 16, 256, 0, stream>>>(image, zwhere, inv, out);
}

// Round 2
// 23.779 us; speedup vs baseline: 1.0132x; 1.0132x over previous
//
#include <hip/hip_runtime.h>

#define H_OBJ 64
#define W_OBJ 64
#define HIN 256
#define WIN 256
#define NCH 3

__device__ __forceinline__ void sample_pixel(
    const float* __restrict__ imgN, float* __restrict__ outN,
    int pix, float x, float y, float zw, float zh, int inv)
{
    const int i = pix >> 6;
    const int j = pix & 63;

    const float gx = -1.0f + (2.0f / 63.0f) * (float)j;
    const float gy = -1.0f + (2.0f / 63.0f) * (float)i;

    float grid_x, grid_y;
    if (inv) {
        grid_x = (gx - x) / zw;
        grid_y = (gy - y) / zh;
    } else {
        grid_x = zw * gx + x;
        grid_y = zh * gy + y;
    }

    float ix = (grid_x + 1.0f) * 0.5f * (float)(WIN - 1);
    float iy = (grid_y + 1.0f) * 0.5f * (float)(HIN - 1);
    ix = fminf(fmaxf(ix, 0.0f), (float)(WIN - 1));
    iy = fminf(fmaxf(iy, 0.0f), (float)(HIN - 1));

    const float ix0f = floorf(ix);
    const float iy0f = floorf(iy);
    const float wx = ix - ix0f;
    const float wy = iy - iy0f;
    const int ix0 = (int)ix0f;
    const int iy0 = (int)iy0f;
    const int ix1 = min(ix0 + 1, WIN - 1);
    const int iy1 = min(iy0 + 1, HIN - 1);

    const float w00 = (1.0f - wx) * (1.0f - wy);
    const float w01 = wx * (1.0f - wy);
    const float w10 = (1.0f - wx) * wy;
    const float w11 = wx * wy;

    const int o00 = iy0 * WIN + ix0;
    const int o01 = iy0 * WIN + ix1;
    const int o10 = iy1 * WIN + ix0;
    const int o11 = iy1 * WIN + ix1;

#pragma unroll
    for (int c = 0; c < NCH; ++c) {
        const float* ch = imgN + c * (HIN * WIN);
        const float v00 = ch[o00];
        const float v01 = ch[o01];
        const float v10 = ch[o10];
        const float v11 = ch[o11];
        __builtin_nontemporal_store(
            v00 * w00 + v01 * w01 + v10 * w10 + v11 * w11,
            &outN[c * (H_OBJ * W_OBJ) + pix]);
    }
}

// 8 blocks of 256 threads per batch; each thread does 2 pixels.
// Swizzle so all 8 blocks of a batch land on the same XCD
// (dispatch slot s -> XCD s%8 heuristic).
__global__ __launch_bounds__(256) void stn_glimpse_kernel(
    const float* __restrict__ image,   // [N,3,256,256]
    const float* __restrict__ zwhere,  // [N,4]  (y,x,h,w)
    const int* __restrict__ inv_p,     // [1]
    float* __restrict__ out,           // [N, 3*64*64]
    int nBatch, int perXcd)            // perXcd = nBatch/8 (0 if not divisible)
{
    const int s = blockIdx.x;
    int n, sub;
    if (perXcd) {
        const int xcd = s & 7;
        const int j   = s >> 3;          // [0, nBatch)
        const int bi  = j % perXcd;
        sub = j / perXcd;                // [0, 8)
        n   = xcd + (bi << 3);
    } else {
        n   = s >> 3;
        sub = s & 7;
    }

    const float zy = zwhere[n * 4 + 0];
    const float zx = zwhere[n * 4 + 1];
    const float zh = zwhere[n * 4 + 2];
    const float zw = zwhere[n * 4 + 3];
    const float y  = zy * 2.0f - 1.0f;
    const float x  = zx * 2.0f - 1.0f;
    const int inv  = *inv_p;   // uniform branch

    const float* imgN = image + (size_t)n * NCH * HIN * WIN;
    float* outN = out + (size_t)n * NCH * (H_OBJ * W_OBJ);

    const int pix0 = (sub << 9) + threadIdx.x;   // sub*512 + t
    sample_pixel(imgN, outN, pix0,       x, y, zw, zh, inv);
    sample_pixel(imgN, outN, pix0 + 256, x, y, zw, zh, inv);
}

extern "C" void kernel_launch(void* const* d_in, const int* in_sizes, int n_in,
                              void* d_out, int out_size, void* d_ws, size_t ws_size,
                              hipStream_t stream) {
    const float* image  = (const float*)d_in[0];
    const float* zwhere = (const float*)d_in[1];
    const int*   inv    = (const int*)d_in[2];
    float*       out    = (float*)d_out;

    const int nBatch = in_sizes[1] / 4;            // 512
    const int perXcd = (nBatch % 8 == 0) ? (nBatch / 8) : 0;
    stn_glimpse_kernel<<<nBatch * 8, 256, 0, stream>>>(
        image, zwhere, inv, out, nBatch, perXcd);
}

// Round 3
// 22.937 us; speedup vs baseline: 1.0504x; 1.0367x over previous
//
#include <hip/hip_runtime.h>

#define H_OBJ 64
#define W_OBJ 64
#define HIN 256
#define WIN 256
#define NCH 3

__device__ __forceinline__ void sample_pixel(
    const float* __restrict__ imgN, float* __restrict__ outN,
    int pix, float x, float y, float zw, float zh, int inv)
{
    const int i = pix >> 6;
    const int j = pix & 63;

    const float gx = -1.0f + (2.0f / 63.0f) * (float)j;
    const float gy = -1.0f + (2.0f / 63.0f) * (float)i;

    float grid_x, grid_y;
    if (inv) {
        grid_x = (gx - x) / zw;
        grid_y = (gy - y) / zh;
    } else {
        grid_x = zw * gx + x;
        grid_y = zh * gy + y;
    }

    float ix = (grid_x + 1.0f) * 0.5f * (float)(WIN - 1);
    float iy = (grid_y + 1.0f) * 0.5f * (float)(HIN - 1);
    ix = fminf(fmaxf(ix, 0.0f), (float)(WIN - 1));
    iy = fminf(fmaxf(iy, 0.0f), (float)(HIN - 1));

    const float ix0f = floorf(ix);
    const float iy0f = floorf(iy);
    const float wx = ix - ix0f;
    const float wy = iy - iy0f;
    const int ix0 = (int)ix0f;
    const int iy0 = (int)iy0f;
    const int iy1 = min(iy0 + 1, HIN - 1);

    // Horizontal tap pair: load float2 at base = min(ix0, WIN-2).
    //  - ix0 < 255: pair = (ix0, ix0+1)  -> v00 = p.x, v01 = p.y
    //  - ix0 = 255: pair = (254, 255)    -> v00 = p.y, v01 = p.y
    const int  base = min(ix0, WIN - 2);
    const bool lo   = (ix0 < WIN - 1);

    const float w00 = (1.0f - wx) * (1.0f - wy);
    const float w01 = wx * (1.0f - wy);
    const float w10 = (1.0f - wx) * wy;
    const float w11 = wx * wy;

    const int o_top = iy0 * WIN + base;
    const int o_bot = iy1 * WIN + base;

#pragma unroll
    for (int c = 0; c < NCH; ++c) {
        const float* ch = imgN + c * (HIN * WIN);
        float2 top, bot;
        __builtin_memcpy(&top, ch + o_top, sizeof(float2));
        __builtin_memcpy(&bot, ch + o_bot, sizeof(float2));
        const float v00 = lo ? top.x : top.y;
        const float v01 = top.y;
        const float v10 = lo ? bot.x : bot.y;
        const float v11 = bot.y;
        __builtin_nontemporal_store(
            v00 * w00 + v01 * w01 + v10 * w10 + v11 * w11,
            &outN[c * (H_OBJ * W_OBJ) + pix]);
    }
}

// 8 blocks of 256 threads per batch; each thread does 2 pixels.
// Swizzle so all 8 blocks of a batch land on the same XCD
// (dispatch slot s -> XCD s%8 heuristic).
__global__ __launch_bounds__(256) void stn_glimpse_kernel(
    const float* __restrict__ image,   // [N,3,256,256]
    const float* __restrict__ zwhere,  // [N,4]  (y,x,h,w)
    const int* __restrict__ inv_p,     // [1]
    float* __restrict__ out,           // [N, 3*64*64]
    int nBatch, int perXcd)            // perXcd = nBatch/8 (0 if not divisible)
{
    const int s = blockIdx.x;
    int n, sub;
    if (perXcd) {
        const int xcd = s & 7;
        const int j   = s >> 3;          // [0, nBatch)
        const int bi  = j % perXcd;
        sub = j / perXcd;                // [0, 8)
        n   = xcd + (bi << 3);
    } else {
        n   = s >> 3;
        sub = s & 7;
    }

    const float zy = zwhere[n * 4 + 0];
    const float zx = zwhere[n * 4 + 1];
    const float zh = zwhere[n * 4 + 2];
    const float zw = zwhere[n * 4 + 3];
    const float y  = zy * 2.0f - 1.0f;
    const float x  = zx * 2.0f - 1.0f;
    const int inv  = *inv_p;   // uniform branch

    const float* imgN = image + (size_t)n * NCH * HIN * WIN;
    float* outN = out + (size_t)n * NCH * (H_OBJ * W_OBJ);

    const int pix0 = (sub << 9) + threadIdx.x;   // sub*512 + t
    sample_pixel(imgN, outN, pix0,       x, y, zw, zh, inv);
    sample_pixel(imgN, outN, pix0 + 256, x, y, zw, zh, inv);
}

extern "C" void kernel_launch(void* const* d_in, const int* in_sizes, int n_in,
                              void* d_out, int out_size, void* d_ws, size_t ws_size,
                              hipStream_t stream) {
    const float* image  = (const float*)d_in[0];
    const float* zwhere = (const float*)d_in[1];
    const int*   inv    = (const int*)d_in[2];
    float*       out    = (float*)d_out;

    const int nBatch = in_sizes[1] / 4;            // 512
    const int perXcd = (nBatch % 8 == 0) ? (nBatch / 8) : 0;
    stn_glimpse_kernel<<<nBatch * 8, 256, 0, stream>>>(
        image, zwhere, inv, out, nBatch, perXcd);
}

// Round 4
// 22.674 us; speedup vs baseline: 1.0626x; 1.0116x over previous
//
#include <hip/hip_runtime.h>

#define H_OBJ 64
#define W_OBJ 64
#define HIN 256
#define WIN 256
#define NCH 3

struct Tap {
    int o_top, o_bot;
    float w00, w01, w10, w11;
    bool lo;
};

__device__ __forceinline__ Tap make_tap(
    int pix, float x, float y, float rw, float rh,
    float zw, float zh, int inv)
{
    const int i = pix >> 6;
    const int j = pix & 63;

    const float gx = -1.0f + (2.0f / 63.0f) * (float)j;
    const float gy = -1.0f + (2.0f / 63.0f) * (float)i;

    float grid_x, grid_y;
    if (inv) {
        grid_x = (gx - x) * rw;
        grid_y = (gy - y) * rh;
    } else {
        grid_x = zw * gx + x;
        grid_y = zh * gy + y;
    }

    float ix = (grid_x + 1.0f) * 0.5f * (float)(WIN - 1);
    float iy = (grid_y + 1.0f) * 0.5f * (float)(HIN - 1);
    ix = fminf(fmaxf(ix, 0.0f), (float)(WIN - 1));
    iy = fminf(fmaxf(iy, 0.0f), (float)(HIN - 1));

    const float ix0f = floorf(ix);
    const float iy0f = floorf(iy);
    const float wx = ix - ix0f;
    const float wy = iy - iy0f;
    const int ix0 = (int)ix0f;
    const int iy0 = (int)iy0f;
    const int iy1 = min(iy0 + 1, HIN - 1);
    const int base = min(ix0, WIN - 2);

    Tap t;
    t.lo    = (ix0 < WIN - 1);
    t.w00   = (1.0f - wx) * (1.0f - wy);
    t.w01   = wx * (1.0f - wy);
    t.w10   = (1.0f - wx) * wy;
    t.w11   = wx * wy;
    t.o_top = iy0 * WIN + base;
    t.o_bot = iy1 * WIN + base;
    return t;
}

// 8 blocks of 256 threads per batch; each thread does 2 pixels.
// All 12 gather loads are issued before any consumption (max MLP).
__global__ __launch_bounds__(256) void stn_glimpse_kernel(
    const float* __restrict__ image,   // [N,3,256,256]
    const float* __restrict__ zwhere,  // [N,4]  (y,x,h,w)
    const int* __restrict__ inv_p,     // [1]
    float* __restrict__ out,           // [N, 3*64*64]
    int nBatch, int perXcd)
{
    const int s = blockIdx.x;
    int n, sub;
    if (perXcd) {
        const int xcd = s & 7;
        const int j   = s >> 3;
        const int bi  = j % perXcd;
        sub = j / perXcd;
        n   = xcd + (bi << 3);
    } else {
        n   = s >> 3;
        sub = s & 7;
    }

    const float zy = zwhere[n * 4 + 0];
    const float zx = zwhere[n * 4 + 1];
    const float zh = zwhere[n * 4 + 2];
    const float zw = zwhere[n * 4 + 3];
    const float y  = zy * 2.0f - 1.0f;
    const float x  = zx * 2.0f - 1.0f;
    const float rw = 1.0f / zw;
    const float rh = 1.0f / zh;
    const int inv  = *inv_p;   // uniform branch

    const float* imgN = image + (size_t)n * NCH * HIN * WIN;
    float* outN = out + (size_t)n * NCH * (H_OBJ * W_OBJ);

    const int pix0 = (sub << 9) + threadIdx.x;   // sub*512 + t
    const Tap t0 = make_tap(pix0,       x, y, rw, rh, zw, zh, inv);
    const Tap t1 = make_tap(pix0 + 256, x, y, rw, rh, zw, zh, inv);

    // Issue all 12 loads back-to-back.
    float2 T0[NCH], B0[NCH], T1[NCH], B1[NCH];
#pragma unroll
    for (int c = 0; c < NCH; ++c) {
        const float* ch = imgN + c * (HIN * WIN);
        __builtin_memcpy(&T0[c], ch + t0.o_top, sizeof(float2));
        __builtin_memcpy(&B0[c], ch + t0.o_bot, sizeof(float2));
        __builtin_memcpy(&T1[c], ch + t1.o_top, sizeof(float2));
        __builtin_memcpy(&B1[c], ch + t1.o_bot, sizeof(float2));
    }

    // Consume.
#pragma unroll
    for (int c = 0; c < NCH; ++c) {
        {
            const float v00 = t0.lo ? T0[c].x : T0[c].y;
            const float v01 = T0[c].y;
            const float v10 = t0.lo ? B0[c].x : B0[c].y;
            const float v11 = B0[c].y;
            __builtin_nontemporal_store(
                v00 * t0.w00 + v01 * t0.w01 + v10 * t0.w10 + v11 * t0.w11,
                &outN[c * (H_OBJ * W_OBJ) + pix0]);
        }
        {
            const float v00 = t1.lo ? T1[c].x : T1[c].y;
            const float v01 = T1[c].y;
            const float v10 = t1.lo ? B1[c].x : B1[c].y;
            const float v11 = B1[c].y;
            __builtin_nontemporal_store(
                v00 * t1.w00 + v01 * t1.w01 + v10 * t1.w10 + v11 * t1.w11,
                &outN[c * (H_OBJ * W_OBJ) + pix0 + 256]);
        }
    }
}

extern "C" void kernel_launch(void* const* d_in, const int* in_sizes, int n_in,
                              void* d_out, int out_size, void* d_ws, size_t ws_size,
                              hipStream_t stream) {
    const float* image  = (const float*)d_in[0];
    const float* zwhere = (const float*)d_in[1];
    const int*   inv    = (const int*)d_in[2];
    float*       out    = (float*)d_out;

    const int nBatch = in_sizes[1] / 4;            // 512
    const int perXcd = (nBatch % 8 == 0) ? (nBatch / 8) : 0;
    stn_glimpse_kernel<<<nBatch * 8, 256, 0, stream>>>(
        image, zwhere, inv, out, nBatch, perXcd);
}